// Round 8
// baseline (140.583 us; speedup 1.0000x reference)
//
#include <hip/hip_runtime.h>
#include <cstdint>
#include <cstddef>

#define NUSERS 100000
#define BB 16384

static __device__ __forceinline__ unsigned short f2bf(float x) {
    unsigned u = __float_as_uint(x);
    u += 0x7FFF + ((u >> 16) & 1);          // round-to-nearest-even
    return (unsigned short)(u >> 16);
}

// accumulate 8 bf16 values (packed in a uint4) into acc[8] with weight w
static __device__ __forceinline__ void acc8(float* acc, uint4 q, float w) {
    acc[0] += w * __uint_as_float(q.x << 16);
    acc[1] += w * __uint_as_float(q.x & 0xffff0000u);
    acc[2] += w * __uint_as_float(q.y << 16);
    acc[3] += w * __uint_as_float(q.y & 0xffff0000u);
    acc[4] += w * __uint_as_float(q.z << 16);
    acc[5] += w * __uint_as_float(q.z & 0xffff0000u);
    acc[6] += w * __uint_as_float(q.w << 16);
    acc[7] += w * __uint_as_float(q.w & 0xffff0000u);
}

// ---------------- K0: per-user attention score Q[u] AND bf16 feature table.
// (unchanged from round 7 — streaming, ~7us)
__global__ __launch_bounds__(256) void k0_scores(
    const float* __restrict__ features, const float* __restrict__ wg1,
    const float* __restrict__ bg1, const float* __restrict__ wg2,
    const float* __restrict__ bg2, float* __restrict__ Q,
    unsigned short* __restrict__ fbf)
{
    __shared__ float frow[16 * 68];   // 16 user rows, padded
    __shared__ float wg1t[16 * 68];   // wg1 transposed [k][d], padded
    const int tid = threadIdx.x;
    const int blk = blockIdx.x;

    const float4 v = ((const float4*)(features + (size_t)blk * 1024))[tid];
    {
        const int row = tid >> 4, q = tid & 15;
        *(float4*)&frow[row * 68 + q * 4] = v;
    }
    {
        const float4 w = ((const float4*)wg1)[tid];
        const int d = tid >> 2, k0 = (tid & 3) * 4;
        wg1t[(k0 + 0) * 68 + d] = w.x;
        wg1t[(k0 + 1) * 68 + d] = w.y;
        wg1t[(k0 + 2) * 68 + d] = w.z;
        wg1t[(k0 + 3) * 68 + d] = w.w;
    }
    {
        ushort4 o;
        o.x = f2bf(v.x); o.y = f2bf(v.y); o.z = f2bf(v.z); o.w = f2bf(v.w);
        *(ushort4*)(fbf + (size_t)blk * 1024 + tid * 4) = o;
    }
    __syncthreads();

    const int k = tid & 15, ul = tid >> 4;
    float x = bg1[k];
    #pragma unroll
    for (int d4 = 0; d4 < 16; ++d4) {
        const float4 f  = *(const float4*)&frow[ul * 68 + d4 * 4];
        const float4 wv = *(const float4*)&wg1t[k * 68 + d4 * 4];
        x += f.x * wv.x + f.y * wv.y + f.z * wv.z + f.w * wv.w;
    }
    float xx = fminf(fmaxf(x, -9.f), 9.f);
    float e2 = __expf(2.f * xx);
    float th = (e2 - 1.f) / (e2 + 1.f);
    float t = th * wg2[k];
    t += __shfl_xor(t, 1);
    t += __shfl_xor(t, 2);
    t += __shfl_xor(t, 4);
    t += __shfl_xor(t, 8);
    if (k == 0) Q[blk * 16 + ul] = t + bg2[0];
}

// ---------------- K1: wide-gather kernel (8 rows per load instruction).
// Round-7 falsifier fired: halving bytes didn't move time -> issue/latency
// chain, not bandwidth. New gather layout: oct = lane>>3 (row-slot 0..7),
// s8 = lane&7 (dim-octet, 16B per lane). One uint4 load = 1KB = 8 full rows.
// Neighbor loop covers 32 rows/iteration with 4 independent loads ->
// avg 2 (max 3) vmcnt waits per wave vs ~3 (max 6) before, and ~7 gather
// instrs vs ~13. Member row + Q issued before the loop to fly under it.
__global__ __launch_bounds__(256) void k1_fuse(
    const int* __restrict__ nodes, const int* __restrict__ hist_u,
    const int* __restrict__ hist_r, const int* __restrict__ hist_m,
    const int* __restrict__ soc_a, const int* __restrict__ soc_m,
    const unsigned short* __restrict__ fbf, const float* __restrict__ r_embed,
    const float* __restrict__ Q, const float* __restrict__ w1,
    const float* __restrict__ b1, float* __restrict__ out)
{
    __shared__ float wvbuf[4][128];   // 2048B per-wave union:
                                      //   lifetime 1: lcomp int[96]
                                      //   lifetime 2: comb  float[128]

    const int tid  = threadIdx.x;
    const int lane = tid & 63;
    const int wv   = tid >> 6;
    const int e    = blockIdx.x * 4 + wv;
    const int sub  = lane & 15;       // matvec role
    const int grp  = lane >> 4;       // matvec role
    const int oct  = lane >> 3;       // gather row-slot 0..7
    const int s8   = lane & 7;        // gather dim-octet (dims s8*8..+7)
    const char* fb = (const char*)fbf;

    int*   lc = (int*)&wvbuf[wv][0];
    float* cb = &wvbuf[wv][0];

    // ---- zero-init merged list (tail entries: offset 0 = row 0) ----
    lc[lane] = 0;
    if (lane < 32) lc[64 + lane] = 0;

    // ---- index loads (issue ASAP) ----
    int nd = (lane < 8) ? nodes[e * 8 + lane] : 0;
    int hu = 0, hr = 0, hmv = 0;
    if (lane < 50) {
        hu  = hist_u[e * 50 + lane];
        hr  = hist_r[e * 50 + lane];
        hmv = hist_m[e * 50 + lane];
    }
    int sa = 0, sk = 0;
    if (lane < 32) {
        sa = soc_a[e * 32 + lane];
        sk = soc_m[e * 32 + lane];
    }

    // ---- ballots / counts ----
    uint64_t hb = __ballot(hmv != 0);
    const int hc = (int)__popcll(hb);
    int hrank = (int)__popcll(hb & ((1ull << lane) - 1));

    uint64_t sbm = __ballot(sk != 0);
    const int scn = (int)__popcll(sbm);
    int srank = (int)__popcll(sbm & ((1ull << lane) - 1));

    const float hw = 0.5f / (float)hc;     // hc >= 1 (mask[:,0]=True)
    const float sw = 0.5f / (float)scn;    // scn >= 1
    const int   n  = hc + scn;             // <= 82

    // ---- merged compaction: hist [0,hc), social [hc,n); byte offsets,
    //      bf16 row = 128B ----
    if (hmv) lc[hrank] = hu << 7;
    if (sk)  lc[hc + srank] = sa << 7;

    // ---- rating counts ----
    const int c0 = (int)__popcll(__ballot(hmv && hr == 0));
    const int c1 = (int)__popcll(__ballot(hmv && hr == 1));
    const int c2 = (int)__popcll(__ballot(hmv && hr == 2));
    const int c3 = (int)__popcll(__ballot(hmv && hr == 3));
    const int c4 = (int)__popcll(__ballot(hmv && hr == 4));

    // ---- read back merged list (ends lcomp lifetime) ----
    int pkA = lc[lane];
    int pkB = lc[64 + (lane & 31)];

    // ---- issue Q gather + member row load EARLY (fly under the loop) ----
    float sc = (lane < 8) ? Q[nd] : -1e30f;
    const int um = __shfl(nd, oct);                    // member row for my slot
    const uint4 mq = *(const uint4*)(fb + ((unsigned)um << 7) + s8 * 16);

    // ---- neighbor loop: 32 rows / iteration, 4 independent 8-row loads ----
    float nb[8] = {0.f, 0.f, 0.f, 0.f, 0.f, 0.f, 0.f, 0.f};
    for (int base = 0; base < n; base += 32) {
        const int b0 = base, b1_ = base + 8, b2 = base + 16, b3 = base + 24;
        // 8-entry windows align to 8 -> never straddle the 64 boundary
        const int off0 = (b0  < 64) ? __shfl(pkA, b0  + oct) : __shfl(pkB, b0  - 64 + oct);
        const int off1 = (b1_ < 64) ? __shfl(pkA, b1_ + oct) : __shfl(pkB, b1_ - 64 + oct);
        const int off2 = (b2  < 64) ? __shfl(pkA, b2  + oct) : __shfl(pkB, b2  - 64 + oct);
        const int off3 = (b3  < 64) ? __shfl(pkA, b3  + oct) : __shfl(pkB, b3  - 64 + oct);
        const uint4 q0 = *(const uint4*)(fb + (unsigned)off0 + s8 * 16);
        const uint4 q1 = *(const uint4*)(fb + (unsigned)off1 + s8 * 16);
        const uint4 q2 = *(const uint4*)(fb + (unsigned)off2 + s8 * 16);
        const uint4 q3 = *(const uint4*)(fb + (unsigned)off3 + s8 * 16);
        const int i0 = b0 + oct, i1 = b1_ + oct, i2 = b2 + oct, i3 = b3 + oct;
        const float w0 = (i0 < hc) ? hw : ((i0 < n) ? sw : 0.f);
        const float w1q= (i1 < hc) ? hw : ((i1 < n) ? sw : 0.f);
        const float w2 = (i2 < hc) ? hw : ((i2 < n) ? sw : 0.f);
        const float w3 = (i3 < hc) ? hw : ((i3 < n) ? sw : 0.f);
        acc8(nb, q0, w0);
        acc8(nb, q1, w1q);
        acc8(nb, q2, w2);
        acc8(nb, q3, w3);
    }

    // ---- softmax over 8 group logits (lanes 0..7; Q landed long ago) ----
    float mx = sc;
    mx = fmaxf(mx, __shfl_xor(mx, 1));
    mx = fmaxf(mx, __shfl_xor(mx, 2));
    mx = fmaxf(mx, __shfl_xor(mx, 4));
    float ex = __expf(sc - mx);
    float sm = ex;
    sm += __shfl_xor(sm, 1);
    sm += __shfl_xor(sm, 2);
    sm += __shfl_xor(sm, 4);
    float al = ex / sm;                 // valid on lanes 0..7

    // ---- self half: alpha-weighted member row (slot oct) ----
    const float am = __shfl(al, oct);
    float sf[8] = {0.f, 0.f, 0.f, 0.f, 0.f, 0.f, 0.f, 0.f};
    acc8(sf, mq, am);

    // ---- cross-slot reduction: sum over oct (lane bits 3..5) ----
    #pragma unroll
    for (int k = 0; k < 8; ++k) {
        nb[k] += __shfl_xor(nb[k], 8);
        nb[k] += __shfl_xor(nb[k], 16);
        nb[k] += __shfl_xor(nb[k], 32);
        sf[k] += __shfl_xor(sf[k], 8);
        sf[k] += __shfl_xor(sf[k], 16);
        sf[k] += __shfl_xor(sf[k], 32);
    }

    // ---- rating-count correction (scaled by 0.5/hc), dims s8*8..+7 ----
    {
        const float4* r4 = (const float4*)r_embed;   // rows of 16 quads
        const int qa = s8 * 2;
        const float4 a0 = r4[0 * 16 + qa], b0 = r4[0 * 16 + qa + 1];
        const float4 a1 = r4[1 * 16 + qa], b1v = r4[1 * 16 + qa + 1];
        const float4 a2 = r4[2 * 16 + qa], b2v = r4[2 * 16 + qa + 1];
        const float4 a3 = r4[3 * 16 + qa], b3v = r4[3 * 16 + qa + 1];
        const float4 a4 = r4[4 * 16 + qa], b4v = r4[4 * 16 + qa + 1];
        const float f0 = hw * (float)c0, f1 = hw * (float)c1, f2 = hw * (float)c2,
                    f3 = hw * (float)c3, f4 = hw * (float)c4;
        nb[0] += f0 * a0.x + f1 * a1.x + f2 * a2.x + f3 * a3.x + f4 * a4.x;
        nb[1] += f0 * a0.y + f1 * a1.y + f2 * a2.y + f3 * a3.y + f4 * a4.y;
        nb[2] += f0 * a0.z + f1 * a1.z + f2 * a2.z + f3 * a3.z + f4 * a4.z;
        nb[3] += f0 * a0.w + f1 * a1.w + f2 * a2.w + f3 * a3.w + f4 * a4.w;
        nb[4] += f0 * b0.x + f1 * b1v.x + f2 * b2v.x + f3 * b3v.x + f4 * b4v.x;
        nb[5] += f0 * b0.y + f1 * b1v.y + f2 * b2v.y + f3 * b3v.y + f4 * b4v.y;
        nb[6] += f0 * b0.z + f1 * b1v.z + f2 * b2v.z + f3 * b3v.z + f4 * b4v.z;
        nb[7] += f0 * b0.w + f1 * b1v.w + f2 * b2v.w + f3 * b3v.w + f4 * b4v.w;
    }

    // ---- park comb row (lcomp dead; wave-local, no barrier) ----
    if (oct == 0) {
        *(float4*)&cb[s8 * 8]     = make_float4(sf[0], sf[1], sf[2], sf[3]);
        *(float4*)&cb[s8 * 8 + 4] = make_float4(sf[4], sf[5], sf[6], sf[7]);
    } else if (oct == 1) {
        *(float4*)&cb[64 + s8 * 8]     = make_float4(nb[0], nb[1], nb[2], nb[3]);
        *(float4*)&cb[64 + s8 * 8 + 4] = make_float4(nb[4], nb[5], nb[6], nb[7]);
    }

    // ---- fused matvec, float4 w1 loads:
    //      lane (grp,sub) accumulates cols 4sub..4sub+3 over k = 4j+grp ----
    float4 p = {0.f, 0.f, 0.f, 0.f};
    #pragma unroll 8
    for (int j = 0; j < 32; ++j) {
        const float  c   = cb[j * 4 + grp];                    // LDS broadcast
        const float4 wv4 = *(const float4*)(w1 + (j * 4 + grp) * 64 + sub * 4);
        p.x += c * wv4.x;
        p.y += c * wv4.y;
        p.z += c * wv4.z;
        p.w += c * wv4.w;
    }
    p.x += __shfl_xor(p.x, 16); p.x += __shfl_xor(p.x, 32);
    p.y += __shfl_xor(p.y, 16); p.y += __shfl_xor(p.y, 32);
    p.z += __shfl_xor(p.z, 16); p.z += __shfl_xor(p.z, 32);
    p.w += __shfl_xor(p.w, 16); p.w += __shfl_xor(p.w, 32);
    if (grp == 0) {
        const float4 bv = *(const float4*)(b1 + sub * 4);
        float4 o;
        o.x = fmaxf(p.x + bv.x, 0.f);
        o.y = fmaxf(p.y + bv.y, 0.f);
        o.z = fmaxf(p.z + bv.z, 0.f);
        o.w = fmaxf(p.w + bv.w, 0.f);
        *(float4*)(out + (size_t)e * 64 + sub * 4) = o;
    }
}

extern "C" void kernel_launch(void* const* d_in, const int* in_sizes, int n_in,
                              void* d_out, int out_size, void* d_ws, size_t ws_size,
                              hipStream_t stream)
{
    const int*   nodes    = (const int*)d_in[0];
    const int*   hu       = (const int*)d_in[1];
    const int*   hr       = (const int*)d_in[2];
    const int*   hm       = (const int*)d_in[3];
    const int*   sa       = (const int*)d_in[4];
    const int*   smk      = (const int*)d_in[5];
    const float* features = (const float*)d_in[6];
    const float* r_embed  = (const float*)d_in[7];
    const float* wg1      = (const float*)d_in[8];
    const float* bg1      = (const float*)d_in[9];
    const float* wg2      = (const float*)d_in[10];
    const float* bg2      = (const float*)d_in[11];
    const float* w1       = (const float*)d_in[12];
    const float* b1       = (const float*)d_in[13];
    float* out = (float*)d_out;

    float*          Q   = (float*)d_ws;                    // 131072 floats (512 KB)
    unsigned short* fbf = (unsigned short*)(Q + 131072);   // 100000*64 bf16 = 12.8 MB

    k0_scores<<<NUSERS / 16, 256, 0, stream>>>(features, wg1, bg1, wg2, bg2, Q, fbf);
    k1_fuse<<<BB / 4, 256, 0, stream>>>(nodes, hu, hr, hm, sa, smk,
                                        fbf, r_embed, Q, w1, b1, out);
}